// Round 5
// baseline (145.505 us; speedup 1.0000x reference)
//
#include <hip/hip_runtime.h>
#include <stdint.h>

// ---------------------------------------------------------------------------
// DetectorKmeans: out[n] = sum_k (pr[k]*var[k]) / ||X[n]-C[k]||^2  - threshold
// N=65536, K=1024, D=512, all fp32 in/out.
// Round 17: schedule axis exhausted (R12/14/15/16 all 82-91us, MfmaUtil
// 31-34%). Attack the OTHER 32us: fuse prep into density. A-staging now
// reg-loads fp32 X (pre-swizzled source), converts on the idle VALU pipe,
// ds_writes the IDENTICAL LDS bytes the old DMA wrote (read side verbatim).
// xsq computed in-kernel from the same loads. Grid = 256 blocks (1/CU),
// panel-INNER loop accumulating rsum across panels -> no partial buffer,
// no reduce kernel, prep shrinks to C-only (~2MB). HBM: ~330MB -> ~135MB,
// serial 30us prep stage eliminated. K-loop schedule = R12 verbatim.
// ---------------------------------------------------------------------------

#define NR 65536
#define KC 1024
#define DD 512

#define BM 256
#define BN 256
#define BK 64
#define NKT (DD / BK)     // 8 K-tiles
#define NPANEL (KC / BN)  // 4 column panels (inner loop now)

#define SLOT_SZ 65536
#define PART_OFF 131072
#define XSQ_OFF  135168
#define LDS_TOTAL (XSQ_OFF + 1024)   // 136192 B

typedef __bf16 bf16;
typedef __attribute__((ext_vector_type(4))) __bf16 bf16x4;
typedef __attribute__((ext_vector_type(8))) __bf16 bf16x8;
typedef __attribute__((ext_vector_type(4))) float f32x4;

__device__ __forceinline__ void gload16(const void* g, void* l) {
  __builtin_amdgcn_global_load_lds(
      (const __attribute__((address_space(1))) unsigned int*)g,
      (__attribute__((address_space(3))) unsigned int*)l, 16, 0, 0);
}

// ---------------------------------------------------------------------------
// prep_c: centers only (2 MB). Cb bf16 row-major, csq, w = pr*var.
__global__ __launch_bounds__(256) void prep_c(
    const float* __restrict__ C, const float* __restrict__ var,
    const float* __restrict__ pr, bf16* __restrict__ Cb,
    float* __restrict__ csq, float* __restrict__ w) {
  const int row  = (int)((blockIdx.x * 256 + threadIdx.x) >> 6);
  const int lane = (int)(threadIdx.x & 63);
  const float* srow = C + (size_t)row * DD;
  bf16* drow = Cb + (size_t)row * DD;

  float4 a = reinterpret_cast<const float4*>(srow)[lane];
  float4 b = reinterpret_cast<const float4*>(srow)[64 + lane];
  float s = a.x * a.x + a.y * a.y + a.z * a.z + a.w * a.w +
            b.x * b.x + b.y * b.y + b.z * b.z + b.w * b.w;
#pragma unroll
  for (int off = 1; off < 64; off <<= 1) s += __shfl_xor(s, off, 64);

  bf16x4 va = {(bf16)a.x, (bf16)a.y, (bf16)a.z, (bf16)a.w};
  bf16x4 vb = {(bf16)b.x, (bf16)b.y, (bf16)b.z, (bf16)b.w};
  reinterpret_cast<bf16x4*>(drow)[lane]      = va;
  reinterpret_cast<bf16x4*>(drow)[64 + lane] = vb;

  if (lane == 0) {
    csq[row] = s;
    w[row]   = pr[row] * var[row];
  }
}

// ---------------------------------------------------------------------------
// LDS per 64 KB slot (verbatim R12):
//   A half h at slot + h*16384: rows {wr*128 + h*64 + r} at rho = wr*64+r,
//     128 B/row; chunk slot s holds global chunk s ^ (rho&7).
//   B kk at slot + 32768 + kk*16384: 256 cols x 64 B; chunk slot s holds
//     global chunk s ^ ((col>>1)&3).  Pre-swizzled source, linear dest.
//
// A row-group g (per lane, 4 rows): g=(h,s2) order {(0,0),(0,1),(1,0),(1,1)}
//   row offset {0, 128, 64, 192}; LDS dest offset g*8192.
// ---------------------------------------------------------------------------

#define AOFF(g) ((g) == 0 ? 0 : (g) == 1 ? 128 * DD : (g) == 2 ? 64 * DD : 192 * DD)

#define A_LOAD(dst, tn)                                                         \
  _Pragma("unroll") for (int g = 0; g < 4; ++g) {                               \
    const float* s_ = aSrcF + AOFF(g) + (tn) * 64;                              \
    dst[2 * g]     = *(const f32x4*)(s_);                                       \
    dst[2 * g + 1] = *(const f32x4*)(s_ + 4);                                   \
  }

#define A_WRITE(src, slotW)                                                     \
  _Pragma("unroll") for (int g = 0; g < 4; ++g) {                               \
    bf16x8 v_;                                                                  \
    _Pragma("unroll") for (int e = 0; e < 4; ++e) {                             \
      v_[e]     = (bf16)src[2 * g][e];                                          \
      v_[4 + e] = (bf16)src[2 * g + 1][e];                                      \
    }                                                                           \
    *(bf16x8*)(smem + (slotW) + g * 8192 + wid * 1024 + lane * 16) = v_;        \
  }

#define XSQACC(src)                                                             \
  _Pragma("unroll") for (int g = 0; g < 4; ++g)                                 \
    _Pragma("unroll") for (int e = 0; e < 4; ++e)                               \
      xa[g] += src[2 * g][e] * src[2 * g][e] +                                  \
               src[2 * g + 1][e] * src[2 * g + 1][e];

#define STAGE_B(kk, tn, slotW)                                                  \
  gload16(bSrc0 + (tn) * 64 + (kk) * 32,                                        \
          smem + (slotW) + 32768 + (kk) * 16384 + wid * 1024);                  \
  gload16(bSrc0 + (size_t)128 * DD + (tn) * 64 + (kk) * 32,                     \
          smem + (slotW) + 32768 + (kk) * 16384 + 8192 + wid * 1024);

#define READ_B(dst, kk, base)                                                   \
  _Pragma("unroll") for (int n = 0; n < 4; ++n)                                 \
    dst[n] = *(const bf16x8*)(smem + (base) + 32768 + (kk) * 16384 + bRd +      \
                              n * 1024);

__global__ __launch_bounds__(512) void density_kernel(
    const float* __restrict__ X, const bf16* __restrict__ Cb,
    const float* __restrict__ csq, const float* __restrict__ w,
    const float* __restrict__ thr, float* __restrict__ out) {
  extern __shared__ char smem[];

  const int tid  = (int)threadIdx.x;
  const int lane = tid & 63;
  const int wid  = tid >> 6;    // 0..7
  const int wr   = wid >> 2;    // 0..1 : 128-row half
  const int wcn  = wid & 3;     // 0..3 : 64-col group
  const int lr   = lane & 15;
  const int lc   = lane >> 4;

  const int rowBase = (int)blockIdx.x * BM;   // grid 256 = 1 block/CU
  const float th = thr[0];

  // A staging source: fp32 X, pre-swizzled chunk (same formula the DMA used)
  const int rowL   = wid * 8 + (lane >> 3);
  const int dchunk = ((lane & 7) ^ (lane >> 3)) << 3;
  const float* aSrcF = X + (size_t)(rowBase + rowL) * DD + dchunk;

  // B staging pre-swizzle (chunk of the 64B row)
  const int chunkSwB = (((lane & 3) ^ ((lane >> 3) & 3)) << 3);

  // fragment read bases (same XOR on the read side) — verbatim R12
  const int aRd  = (wr * 64 + lr) * 128;
  const int aSw0 = ((lc ^ (lr & 7)) << 4);
  const int aSw1 = (((4 | lc) ^ (lr & 7)) << 4);
  const int bRd  = (wcn * 64 + lr) * 64 + ((lc ^ ((lr >> 1) & 3)) << 4);

  float rsum[8][4];
#pragma unroll
  for (int m = 0; m < 8; ++m)
#pragma unroll
    for (int j = 0; j < 4; ++j) rsum[m][j] = 0.f;

  float xa[4] = {0.f, 0.f, 0.f, 0.f};
  f32x4 xrv[8];
  f32x4 areg[8];

#pragma unroll 1
  for (int p = 0; p < NPANEL; ++p) {
    const int colBase = p * BN;
    const bf16* bSrc0 = Cb + (size_t)(colBase + wid * 16 + (lane >> 2)) * DD +
                        chunkSwB;

    f32x4 acc[8][4];
#pragma unroll
    for (int m = 0; m < 8; ++m)
#pragma unroll
      for (int n = 0; n < 4; ++n) acc[m][n] = (f32x4){0.f, 0.f, 0.f, 0.f};

    // ---- prologue: stage tile 0 into slot 0 ----
    A_LOAD(areg, 0);
    STAGE_B(0, 0, 0);
    STAGE_B(1, 0, 0);
    asm volatile("s_waitcnt vmcnt(0)" ::: "memory");
    A_WRITE(areg, 0);
    if (p == 0) { XSQACC(areg); }
    asm volatile("s_waitcnt lgkmcnt(0)" ::: "memory");
    __builtin_amdgcn_s_barrier();

    // ---- main loop: R12 schedule verbatim (1 phase + 1 barrier per tile) --
#pragma unroll 1
    for (int t = 0; t < NKT; ++t) {
      const int slotR = (t & 1) << 16;
      const int slotW = slotR ^ SLOT_SZ;
      const bool st = (t + 1) < NKT;

      if (st) {
        A_LOAD(areg, t + 1);
        STAGE_B(0, t + 1, slotW);
        STAGE_B(1, t + 1, slotW);
      }

      bf16x8 bgK0[4], bgK1[4];
      READ_B(bgK0, 0, slotR);
      READ_B(bgK1, 1, slotR);

      __builtin_amdgcn_s_setprio(1);
#pragma unroll
      for (int h = 0; h < 2; ++h) {
#pragma unroll
        for (int mi = 0; mi < 4; ++mi) {
          const bf16x8 a0 = *(const bf16x8*)(smem + slotR + h * 16384 + aRd +
                                             mi * 2048 + aSw0);
          const bf16x8 a1 = *(const bf16x8*)(smem + slotR + h * 16384 + aRd +
                                             mi * 2048 + aSw1);
#pragma unroll
          for (int n = 0; n < 4; ++n)
            acc[h * 4 + mi][n] = __builtin_amdgcn_mfma_f32_16x16x32_bf16(
                a0, bgK0[n], acc[h * 4 + mi][n], 0, 0, 0);
#pragma unroll
          for (int n = 0; n < 4; ++n)
            acc[h * 4 + mi][n] = __builtin_amdgcn_mfma_f32_16x16x32_bf16(
                a1, bgK1[n], acc[h * 4 + mi][n], 0, 0, 0);
        }
      }
      __builtin_amdgcn_s_setprio(0);

      if (st) {
        asm volatile("s_waitcnt vmcnt(0)" ::: "memory");
        A_WRITE(areg, slotW);
        if (p == 0) { XSQACC(areg); }
        asm volatile("s_waitcnt lgkmcnt(0)" ::: "memory");
        __builtin_amdgcn_s_barrier();
      }
    }

    // ---- panel 0 only: finalize xsq (from the same loads), park in LDS ----
    if (p == 0) {
      // reduce over the 8 lanes (lane&7 group) sharing each row
#pragma unroll
      for (int off = 1; off < 8; off <<= 1) {
#pragma unroll
        for (int g = 0; g < 4; ++g) xa[g] += __shfl_xor(xa[g], off, 64);
      }
      float* xsqS = (float*)(smem + XSQ_OFF);
      if ((lane & 7) == 0) {
        const int r0 = wid * 8 + (lane >> 3);
        xsqS[r0]       = xa[0];
        xsqS[r0 + 128] = xa[1];
        xsqS[r0 + 64]  = xa[2];
        xsqS[r0 + 192] = xa[3];
      }
      __syncthreads();
#pragma unroll
      for (int m = 0; m < 8; ++m)
        xrv[m] = *(const f32x4*)(xsqS + wr * 128 + m * 16 + lc * 4);
    }

    // ---- per-panel density accumulation (VALU only, no sync) ----
#pragma unroll
    for (int n = 0; n < 4; ++n) {
      const int gc = colBase + wcn * 64 + n * 16 + lr;
      const float cs = csq[gc];
      const float ww = w[gc];
#pragma unroll
      for (int m = 0; m < 8; ++m)
#pragma unroll
        for (int j = 0; j < 4; ++j) {
          const float sq = xrv[m][j] + cs - 2.f * acc[m][n][j];
          rsum[m][j] += ww * __builtin_amdgcn_rcpf(sq);
        }
    }
  }

  // ---- final cross-lane + cross-wave reduction, single out write ----
#pragma unroll
  for (int m = 0; m < 8; ++m)
#pragma unroll
    for (int j = 0; j < 4; ++j) {
      float v = rsum[m][j];
      v += __shfl_xor(v, 1, 64);
      v += __shfl_xor(v, 2, 64);
      v += __shfl_xor(v, 4, 64);
      v += __shfl_xor(v, 8, 64);
      rsum[m][j] = v;
    }

  float* part = (float*)(smem + PART_OFF);   // [4 wcn][256 rows]
  __syncthreads();
  if (lr == 0) {
#pragma unroll
    for (int m = 0; m < 8; ++m)
#pragma unroll
      for (int j = 0; j < 4; ++j)
        part[wcn * 256 + wr * 128 + m * 16 + lc * 4 + j] = rsum[m][j];
  }
  __syncthreads();
  if (tid < BM) {
    const float s = part[tid] + part[256 + tid] + part[512 + tid] + part[768 + tid];
    out[rowBase + tid] = s - th;
  }
}

// ---------------------------------------------------------------------------
extern "C" void kernel_launch(void* const* d_in, const int* in_sizes, int n_in,
                              void* d_out, int out_size, void* d_ws, size_t ws_size,
                              hipStream_t stream) {
  const float* X   = (const float*)d_in[0];
  const float* C   = (const float*)d_in[1];
  const float* var = (const float*)d_in[2];
  const float* pr  = (const float*)d_in[3];
  const float* thr = (const float*)d_in[4];
  float* out = (float*)d_out;

  char* ws = (char*)d_ws;
  bf16* Cb   = (bf16*)(ws);
  float* csq = (float*)(ws + (size_t)KC * DD * 2);
  float* w   = csq + KC;

  prep_c<<<KC / 4, 256, 0, stream>>>(C, var, pr, Cb, csq, w);
  density_kernel<<<NR / BM, 512, LDS_TOTAL, stream>>>(X, Cb, csq, w, thr, out);
}

// Round 6
// 118.854 us; speedup vs baseline: 1.2242x; 1.2242x over previous
//
#include <hip/hip_runtime.h>
#include <stdint.h>

// ---------------------------------------------------------------------------
// DetectorKmeans: out[n] = sum_k (pr[k]*var[k]) / ||X[n]-C[k]||^2  - threshold
// N=65536, K=1024, D=512, all fp32 in/out.
// Round 18: occupancy attack. All schedules stall at 2 waves/SIMD because
// three ~2400cyc pipes (MFMA / LDS-read / VMEM staging) can't be covered by
// 2 waves. Shrink per-wave acc 128->64 f32 (wave tile 64x64), cap regs at
// 128 via __launch_bounds__(512,4) -> 2 blocks/CU, 4 waves/SIMD. Block =
// 128x256, BK=32, two 24KB slots (51KB/block). Staging path + swizzles =
// R14 (proven, 0 conflicts); K-loop schedule = R12 (single phase, vmcnt(0),
// drain covered by the co-resident block). prep/reduce unchanged.
// ---------------------------------------------------------------------------

#define NR 65536
#define KC 1024
#define DD 512

#define BM 128
#define BN 256
#define BK 32
#define NKT (DD / BK)     // 16 K-tiles
#define NPART (KC / BN)   // 4 column panels

#define SLOT_SZ 24576     // A 128x32x2 (8 KB) + B 256x32x2 (16 KB)
#define PART_OFF 49152    // after 2 slots
#define LDS_TOTAL (PART_OFF + 2048)   // + [4][128] f32 partial = 51200 B

typedef __bf16 bf16;
typedef __attribute__((ext_vector_type(4))) __bf16 bf16x4;
typedef __attribute__((ext_vector_type(8))) __bf16 bf16x8;
typedef __attribute__((ext_vector_type(4))) float f32x4;

__device__ __forceinline__ void gload16(const void* g, void* l) {
  __builtin_amdgcn_global_load_lds(
      (const __attribute__((address_space(1))) unsigned int*)g,
      (__attribute__((address_space(3))) unsigned int*)l, 16, 0, 0);
}

// ---------------------------------------------------------------------------
__global__ __launch_bounds__(256) void prep_kernel(
    const float* __restrict__ X, const float* __restrict__ C,
    const float* __restrict__ var, const float* __restrict__ pr,
    bf16* __restrict__ Xb, bf16* __restrict__ Cb,
    float* __restrict__ xsq, float* __restrict__ csq, float* __restrict__ w) {
  const int row  = (int)((blockIdx.x * 256 + threadIdx.x) >> 6);
  const int lane = (int)(threadIdx.x & 63);
  const bool isX = row < NR;
  const float* srow = isX ? (X + (size_t)row * DD) : (C + (size_t)(row - NR) * DD);
  bf16* drow = isX ? (Xb + (size_t)row * DD) : (Cb + (size_t)(row - NR) * DD);

  float4 a = reinterpret_cast<const float4*>(srow)[lane];
  float4 b = reinterpret_cast<const float4*>(srow)[64 + lane];
  float s = a.x * a.x + a.y * a.y + a.z * a.z + a.w * a.w +
            b.x * b.x + b.y * b.y + b.z * b.z + b.w * b.w;
#pragma unroll
  for (int off = 1; off < 64; off <<= 1) s += __shfl_xor(s, off, 64);

  bf16x4 va = {(bf16)a.x, (bf16)a.y, (bf16)a.z, (bf16)a.w};
  bf16x4 vb = {(bf16)b.x, (bf16)b.y, (bf16)b.z, (bf16)b.w};
  reinterpret_cast<bf16x4*>(drow)[lane]      = va;
  reinterpret_cast<bf16x4*>(drow)[64 + lane] = vb;

  if (lane == 0) {
    if (isX) {
      xsq[row] = s;
    } else {
      const int k = row - NR;
      csq[k] = s;
      w[k]   = pr[k] * var[k];
    }
  }
}

// ---------------------------------------------------------------------------
// LDS per 24 KB slot:
//   A at [0, 8192):     128 rows x 64 B (BK=32); row r's 16-B chunk c lives
//                       at slot c ^ ((r>>1)&3)  (2-way-free b128 reads).
//   B at [8192, 24576): 256 cols x 64 B, same chunk swizzle.
//   Pre-swizzled gload source, linear DMA dest (wave-uniform base + lane*16).
//   Wave wid stages 16 consecutive rows per gload (1 KB each).
// ---------------------------------------------------------------------------

#define STAGE(tn, slotW)                                                        \
  gload16(aSrc0 + (tn) * 32,                 smem + (slotW) + wid * 1024);      \
  gload16(bSrc0 + (tn) * 32,                 smem + (slotW) + 8192 + wid * 1024);\
  gload16(bSrc0 + (size_t)128 * DD + (tn) * 32,                                 \
          smem + (slotW) + 16384 + wid * 1024);

__global__ __launch_bounds__(512, 4) void density_kernel(
    const bf16* __restrict__ Xb, const bf16* __restrict__ Cb,
    const float* __restrict__ xsq, const float* __restrict__ csq,
    const float* __restrict__ w, float* __restrict__ partial) {
  extern __shared__ char smem[];

  const int tid  = (int)threadIdx.x;
  const int lane = tid & 63;
  const int wid  = tid >> 6;    // 0..7
  const int wr   = wid >> 2;    // 0..1 : 64-row half
  const int wcn  = wid & 3;     // 0..3 : 64-col group
  const int lr   = lane & 15;
  const int lc   = lane >> 4;

  // XCD-aware bijective swizzle: grid 2048, 8 XCDs, 256 blocks each.
  const int bid   = (int)blockIdx.x;
  const int swz   = (bid & 7) * 256 + (bid >> 3);
  const int ntile = swz >> 9;     // 0..3   panel
  const int mtile = swz & 511;    // 0..511 row tile
  const int rowBase = mtile * BM;
  const int colBase = ntile * BN;

  // staging sources (pre-swizzled chunk; linear DMA dest)
  const int chunkSw = (((lane & 3) ^ ((lane >> 3) & 3)) << 3);
  const bf16* aSrc0 = Xb + (size_t)(rowBase + wid * 16 + (lane >> 2)) * DD + chunkSw;
  const bf16* bSrc0 = Cb + (size_t)(colBase + wid * 16 + (lane >> 2)) * DD + chunkSw;

  // fragment read bases (same XOR on the read side)
  const int rdSw = ((lc ^ ((lr >> 1) & 3)) << 4);
  const int aRd  = (wr * 64 + lr) * 64 + rdSw;             // + mi*1024
  const int bRd  = 8192 + (wcn * 64 + lr) * 64 + rdSw;     // + n*1024

  f32x4 acc[4][4];
#pragma unroll
  for (int m = 0; m < 4; ++m)
#pragma unroll
    for (int n = 0; n < 4; ++n) acc[m][n] = (f32x4){0.f, 0.f, 0.f, 0.f};

  // ---- prologue: stage tile 0 into slot 0 ----
  STAGE(0, 0);
  asm volatile("s_waitcnt vmcnt(0)" ::: "memory");
  __builtin_amdgcn_s_barrier();

  // ---- main loop: single phase + single barrier per K-tile (R12 proven) --
#pragma unroll 1
  for (int t = 0; t < NKT; ++t) {
    const int slotR = (t & 1) ? SLOT_SZ : 0;
    const int slotW = slotR ^ SLOT_SZ;
    const bool st = (t + 1) < NKT;

    if (st) { STAGE(t + 1, slotW); }

    bf16x8 bg[4];
#pragma unroll
    for (int n = 0; n < 4; ++n)
      bg[n] = *(const bf16x8*)(smem + slotR + bRd + n * 1024);

    __builtin_amdgcn_s_setprio(1);
#pragma unroll
    for (int mi = 0; mi < 4; ++mi) {
      const bf16x8 a = *(const bf16x8*)(smem + slotR + aRd + mi * 1024);
#pragma unroll
      for (int n = 0; n < 4; ++n)
        acc[mi][n] = __builtin_amdgcn_mfma_f32_16x16x32_bf16(
            a, bg[n], acc[mi][n], 0, 0, 0);
    }
    __builtin_amdgcn_s_setprio(0);

    if (st) {
      asm volatile("s_waitcnt vmcnt(0)" ::: "memory");   // t+1 landed
      __builtin_amdgcn_s_barrier();                      // other block covers
    }
  }

  // ---- epilogue: density partials for this wave's 64x64 output ----
  float xr[4][4];
#pragma unroll
  for (int m = 0; m < 4; ++m)
#pragma unroll
    for (int j = 0; j < 4; ++j)
      xr[m][j] = xsq[rowBase + wr * 64 + m * 16 + lc * 4 + j];

  float rsum[4][4];
#pragma unroll
  for (int m = 0; m < 4; ++m)
#pragma unroll
    for (int j = 0; j < 4; ++j) rsum[m][j] = 0.f;

#pragma unroll
  for (int n = 0; n < 4; ++n) {
    const int gc = colBase + wcn * 64 + n * 16 + lr;
    const float cs = csq[gc];
    const float ww = w[gc];
#pragma unroll
    for (int m = 0; m < 4; ++m)
#pragma unroll
      for (int j = 0; j < 4; ++j) {
        const float sq = xr[m][j] + cs - 2.f * acc[m][n][j];
        rsum[m][j] += ww * __builtin_amdgcn_rcpf(sq);
      }
  }
#pragma unroll
  for (int m = 0; m < 4; ++m)
#pragma unroll
    for (int j = 0; j < 4; ++j) {
      float v = rsum[m][j];
      v += __shfl_xor(v, 1, 64);
      v += __shfl_xor(v, 2, 64);
      v += __shfl_xor(v, 4, 64);
      v += __shfl_xor(v, 8, 64);
      rsum[m][j] = v;
    }

  float* part = (float*)(smem + PART_OFF);   // [4 wcn][128 rows]
  __syncthreads();
  if (lr == 0) {
#pragma unroll
    for (int m = 0; m < 4; ++m)
#pragma unroll
      for (int j = 0; j < 4; ++j)
        part[wcn * 128 + wr * 64 + m * 16 + lc * 4 + j] = rsum[m][j];
  }
  __syncthreads();
  if (tid < BM) {
    const float s = part[tid] + part[128 + tid] + part[256 + tid] + part[384 + tid];
    partial[(size_t)ntile * NR + rowBase + tid] = s;
  }
}

// ---------------------------------------------------------------------------
__global__ __launch_bounds__(256) void reduce_kernel(
    const float* __restrict__ partial, const float* __restrict__ thr,
    float* __restrict__ out) {
  const int n = (int)(blockIdx.x * 256 + threadIdx.x);
  float s = 0.f;
#pragma unroll
  for (int g = 0; g < NPART; ++g) s += partial[(size_t)g * NR + n];
  out[n] = s - thr[0];
}

// ---------------------------------------------------------------------------
extern "C" void kernel_launch(void* const* d_in, const int* in_sizes, int n_in,
                              void* d_out, int out_size, void* d_ws, size_t ws_size,
                              hipStream_t stream) {
  const float* X   = (const float*)d_in[0];
  const float* C   = (const float*)d_in[1];
  const float* var = (const float*)d_in[2];
  const float* pr  = (const float*)d_in[3];
  const float* thr = (const float*)d_in[4];
  float* out = (float*)d_out;

  char* ws = (char*)d_ws;
  bf16* Xb   = (bf16*)(ws);
  bf16* Cb   = (bf16*)(ws + (size_t)NR * DD * 2);
  float* xsq = (float*)(ws + (size_t)NR * DD * 2 + (size_t)KC * DD * 2);
  float* csq = xsq + NR;
  float* w   = csq + KC;
  float* partial = w + KC;   // 4 * 65536 floats = 1 MB

  prep_kernel<<<(NR + KC) / 4, 256, 0, stream>>>(X, C, var, pr, Xb, Cb, xsq, csq, w);
  density_kernel<<<(NR / BM) * NPART, 512, LDS_TOTAL, stream>>>(
      Xb, Cb, xsq, csq, w, partial);
  reduce_kernel<<<NR / 256, 256, 0, stream>>>(partial, thr, out);
}